// Round 1
// baseline (201.603 us; speedup 1.0000x reference)
//
#include <hip/hip_runtime.h>

// Problem constants (fixed by setup_inputs): B=4, D=32, H=512, W=512, K=16
#define B_ 4
#define D_ 32
#define H_ 512
#define W_ 512
#define K_ 16
#define N_ (H_ * W_)    // 262144 pixels per image
#define NQ_ (N_ / 4)    // 65536 float4-quads per image
#define NBLK_ 256       // attract blocks per image (256 blk * 256 thr * 4 px = N_)
#define EPAD 33         // sE row pad: bank=(k*33+d)%32 distinct for distinct k

// Workspace layout (float indices):
#define WS_SUM  0      // [64]  (unused now, kept for layout compat)
#define WS_CNT  64     // [64]
#define WS_E2   128    // [64]  |E_k|^2       (written by attract blockIdx.x==0)
#define WS_LAB  192    // [64]  (unused now)
#define WS_E    264    // [2048] E[b][k][d]   (written by attract blockIdx.x==0)
#define WS_PART 4096   // [B*NBLK*32] per-block partials: [b][blk][k]=sum, [16+k]=cnt

typedef float vfloat4 __attribute__((ext_vector_type(4)));
typedef int vint4 __attribute__((ext_vector_type(4)));

__device__ inline vfloat4 nt_load_f4(const float* p) {
  return __builtin_nontemporal_load((const vfloat4*)p);
}
__device__ inline vint4 nt_load_i4(const int* p) {
  return __builtin_nontemporal_load((const vint4*)p);
}

// Fused: per-block E gather (was setup_kernel) + attract accumulation.
__global__ __launch_bounds__(256) void attract_kernel(
    const float* __restrict__ outp, const int* __restrict__ target,
    const int* __restrict__ centers, float* __restrict__ ws) {
  const int b = blockIdx.y;
  const int tid = threadIdx.x;
  __shared__ float sE[K_ * EPAD];
  __shared__ float se2[K_];
  __shared__ int slab[K_];
  __shared__ int scy[K_], scx[K_];
  __shared__ float bs[K_];
  __shared__ float bc[K_];

  // --- Prologue: gather E/e2/labels directly from global (L2-hot after the
  // first blocks; ~2.5 KB per block). Replaces the separate setup_kernel.
  if (tid < 2 * K_) {
    const int v = centers[b * (2 * K_) + tid];
    if (tid & 1) scx[tid >> 1] = v; else scy[tid >> 1] = v;
  }
  __syncthreads();
  {
    const int k = tid >> 4, d0 = tid & 15;           // 256 threads -> 2 elems each
    const size_t cbase = ((size_t)b * D_ * H_ + scy[k]) * W_ + scx[k];
    const float v0 = outp[cbase + (size_t)d0 * N_];
    const float v1 = outp[cbase + (size_t)(d0 + 16) * N_];
    sE[k * EPAD + d0] = v0;
    sE[k * EPAD + d0 + 16] = v1;
    float p = fmaf(v0, v0, v1 * v1);
#pragma unroll
    for (int off = 1; off < 16; off <<= 1) p += __shfl_xor(p, off, 64);
    if (blockIdx.x == 0) {  // export for final_kernel
      ws[WS_E + (b * K_ + k) * D_ + d0] = v0;
      ws[WS_E + (b * K_ + k) * D_ + d0 + 16] = v1;
      if ((tid & 15) == 0) ws[WS_E2 + b * K_ + k] = p;
    }
    if ((tid & 15) == 0) se2[k] = p;
    if (tid < K_) {
      slab[tid] = target[(size_t)b * N_ + scy[tid] * W_ + scx[tid]];
      bs[tid] = 0.0f;
      bc[tid] = 0.0f;
    }
  }
  __syncthreads();

  // --- Main loop: one float4-quad of pixels per thread.
  const int q = blockIdx.x * 256 + tid;  // [0, NQ_)
  const float* xb = outp + (size_t)b * D_ * N_;
  const vint4 lab4 = nt_load_i4(target + (size_t)b * N_ + 4 * q);
  const int labv[4] = {lab4.x, lab4.y, lab4.z, lab4.w};

  int kf[4], nm[4];
#pragma unroll
  for (int j = 0; j < 4; ++j) { kf[j] = 0; nm[j] = 0; }
#pragma unroll
  for (int k = 0; k < K_; ++k) {
    const int lk = slab[k];
#pragma unroll
    for (int j = 0; j < 4; ++j) {
      if (labv[j] == lk) { if (nm[j] == 0) kf[j] = k; nm[j]++; }
    }
  }

  float dot[4] = {0.f, 0.f, 0.f, 0.f};
  float x2[4] = {0.f, 0.f, 0.f, 0.f};
#pragma unroll
  for (int d = 0; d < D_; ++d) {
    const vfloat4 x = nt_load_f4(xb + (size_t)d * N_ + 4 * q);
    const float xs[4] = {x.x, x.y, x.z, x.w};
#pragma unroll
    for (int j = 0; j < 4; ++j) {
      const float e = sE[kf[j] * EPAD + d];
      dot[j] = fmaf(xs[j], e, dot[j]);
      x2[j] = fmaf(xs[j], xs[j], x2[j]);
    }
  }

  float hv[4];
#pragma unroll
  for (int j = 0; j < 4; ++j) {
    const float d2 = x2[j] + se2[kf[j]] - 2.0f * dot[j];
    const float h = fmaxf(sqrtf(fmaxf(d2, 0.0f)) - 0.1f, 0.0f);  // DELTA_A=0.1
    hv[j] = (nm[j] > 0) ? h : 0.0f;
  }

  // --- Epilogue: labels are constant over 128-pixel runs = 32-lane groups.
  // Uniform 32-lane group -> butterfly-sum + ONE atomic per group (replaces
  // 64-way-serialized same-address LDS atomics).
  const bool same = (kf[0] == kf[1]) & (kf[1] == kf[2]) & (kf[2] == kf[3]);
  float hsum = hv[0] + hv[1] + hv[2] + hv[3];
  float csum = (float)((nm[0] > 0) + (nm[1] > 0) + (nm[2] > 0) + (nm[3] > 0));
  int gi = same ? (kf[0] + 1) : 0;  // 0 = not uniform / invalid
#pragma unroll
  for (int off = 1; off < 32; off <<= 1) {
    const int o = __shfl_xor(gi, off, 64);
    if (o != gi) gi = 0;
  }
  if (gi != 0) {  // whole 32-lane group shares one k
#pragma unroll
    for (int off = 1; off < 32; off <<= 1) {
      hsum += __shfl_xor(hsum, off, 64);
      csum += __shfl_xor(csum, off, 64);
    }
    if ((tid & 31) == 0 && csum > 0.0f) {
      atomicAdd(&bs[gi - 1], hsum);
      atomicAdd(&bc[gi - 1], csum);
    }
  } else if (same) {
    if (csum > 0.0f) {
      atomicAdd(&bs[kf[0]], hsum);
      atomicAdd(&bc[kf[0]], csum);
    }
  } else {
#pragma unroll
    for (int j = 0; j < 4; ++j) {
      if (nm[j] > 0) {
        atomicAdd(&bs[kf[j]], hv[j]);
        atomicAdd(&bc[kf[j]], 1.0f);
      }
    }
  }

  // Rare general case: duplicate-label centers (never taken on this input).
  const bool extra = (nm[0] > 1) | (nm[1] > 1) | (nm[2] > 1) | (nm[3] > 1);
  if (__any(extra)) {
    for (int k = 0; k < K_; ++k) {
      bool need[4]; bool anyn = false;
#pragma unroll
      for (int j = 0; j < 4; ++j) {
        need[j] = (nm[j] > 1) && (labv[j] == slab[k]) && (k != kf[j]);
        anyn |= need[j];
      }
      if (__any(anyn)) {
        float dt[4] = {0.f, 0.f, 0.f, 0.f};
        for (int d = 0; d < D_; ++d) {
          const vfloat4 x = nt_load_f4(xb + (size_t)d * N_ + 4 * q);
          const float e = sE[k * EPAD + d];
          dt[0] = fmaf(x.x, e, dt[0]);
          dt[1] = fmaf(x.y, e, dt[1]);
          dt[2] = fmaf(x.z, e, dt[2]);
          dt[3] = fmaf(x.w, e, dt[3]);
        }
#pragma unroll
        for (int j = 0; j < 4; ++j) {
          if (need[j]) {
            const float d2 = x2[j] + se2[k] - 2.0f * dt[j];
            atomicAdd(&bs[k], fmaxf(sqrtf(fmaxf(d2, 0.0f)) - 0.1f, 0.0f));
            atomicAdd(&bc[k], 1.0f);
          }
        }
      }
    }
  }
  __syncthreads();

  if (tid < 2 * K_) {
    float* p = ws + WS_PART + ((size_t)b * NBLK_ + blockIdx.x) * (2 * K_);
    p[tid] = (tid < K_) ? bs[tid] : bc[tid - K_];
  }
}

// Fused: deterministic partial reduction (was reduce_kernel) + finalization.
__global__ __launch_bounds__(256) void final_kernel(const float* __restrict__ ws,
                                                    float* __restrict__ out) {
  const int tid = threadIdx.x;
  __shared__ float sE[B_ * K_ * D_];
  __shared__ float ps[4][64], pc[4][64];
  __shared__ float sred[256];
  __shared__ float srep[B_];
  __shared__ float sreg[B_];
  __shared__ float ssa[B_];

  for (int i = tid; i < B_ * K_ * D_; i += 256) sE[i] = ws[WS_E + i];

  // Phase 1: reduce NBLK_ partials per (b,k); 4 threads per pair, 64 each.
  const int pair = tid & 63, quarter = tid >> 6;
  const int pb = pair >> 4, pk = pair & 15;
  {
    const float* base =
        ws + WS_PART + ((size_t)pb * NBLK_ + quarter * 64) * (2 * K_);
    float s = 0.0f, c = 0.0f;
#pragma unroll 4
    for (int i = 0; i < 64; ++i) {
      s += base[i * (2 * K_) + pk];
      c += base[i * (2 * K_) + K_ + pk];
    }
    ps[quarter][pair] = s;
    pc[quarter][pair] = c;
  }
  __syncthreads();  // also covers sE

  if (tid < 64) {
    const float s = ps[0][tid] + ps[1][tid] + ps[2][tid] + ps[3][tid];
    const float c = pc[0][tid] + pc[1][tid] + pc[2][tid] + pc[3][tid];
    float v = s / fmaxf(c - 1.0f, 1.0f);
#pragma unroll
    for (int off = 1; off < K_; off <<= 1) v += __shfl_xor(v, off, 64);
    if ((tid & 15) == 0) ssa[tid >> 4] = v;
  }
  __syncthreads();

  // Phase 2: repulse — 256 pairs per image, tree-reduce per b.
  const int i = tid >> 4, j = tid & 15;
  for (int b = 0; b < B_; ++b) {
    float dotv = 0.0f;
#pragma unroll 8
    for (int d = 0; d < D_; ++d)
      dotv = fmaf(sE[(b * K_ + i) * D_ + d], sE[(b * K_ + j) * D_ + d], dotv);
    const float d2 = ws[WS_E2 + b * K_ + i] + ws[WS_E2 + b * K_ + j] - 2.0f * dotv;
    sred[tid] = fmaxf(1.0f - sqrtf(fmaxf(d2, 0.0f)), 0.0f);  // DELTA_R=1.0
    __syncthreads();
    for (int s = 128; s > 0; s >>= 1) {
      if (tid < s) sred[tid] += sred[tid + s];
      __syncthreads();
    }
    if (tid == 0) srep[b] = sred[0] - (float)K_;
    __syncthreads();
  }

  // Reg: sqrt(|E|^2) summed per b.
  sred[tid] = (tid < B_ * K_) ? sqrtf(fmaxf(ws[WS_E2 + tid], 0.0f)) : 0.0f;
  __syncthreads();
  if (tid < B_) {
    float sg = 0.0f;
    for (int k = 0; k < K_; ++k) sg += sred[tid * K_ + k];
    sreg[tid] = sg;
  }
  __syncthreads();

  if (tid == 0) {
    float att = 0.0f, rep = 0.0f, reg = 0.0f;
    for (int b = 0; b < B_; ++b) {
      att = (att + ssa[b]) / (float)K_;
      rep = (rep + srep[b]) / (float)(K_ * (K_ - 1));
      reg = (reg + sreg[b]) / (float)K_;
    }
    out[0] = att + rep + 0.001f * reg;  // ALPHA=BETA=1, GAMMA=0.001
    out[1] = att;
    out[2] = rep;
  }
}

extern "C" void kernel_launch(void* const* d_in, const int* in_sizes, int n_in,
                              void* d_out, int out_size, void* d_ws, size_t ws_size,
                              hipStream_t stream) {
  const float* outp = (const float*)d_in[0];
  const int* target = (const int*)d_in[1];
  const int* centers = (const int*)d_in[2];
  float* ws = (float*)d_ws;
  float* out = (float*)d_out;

  attract_kernel<<<dim3(NBLK_, B_), 256, 0, stream>>>(outp, target, centers, ws);
  final_kernel<<<1, 256, 0, stream>>>(ws, out);
}